// Round 2
// baseline (361.959 us; speedup 1.0000x reference)
//
#include <hip/hip_runtime.h>
#include <stdint.h>
#include <math.h>

#define SEQ 2048
#define HID 2048
#define NH 16
#define NKV 8
#define HD 256
#define QSZ 4096
#define QKVN 8192

typedef __attribute__((ext_vector_type(4))) float f32x4;
typedef _Float16 f16x8 __attribute__((ext_vector_type(8)));
typedef unsigned short u16;

__device__ __forceinline__ u16 f2h(float f) {
  _Float16 h = (_Float16)f;
  return __builtin_bit_cast(u16, h);
}
__device__ __forceinline__ float h2f(u16 b) {
  return (float)__builtin_bit_cast(_Float16, b);
}
// async global->LDS, 16B per lane; LDS dest is wave-uniform base + lane*16
__device__ __forceinline__ void glds16(const void* g, void* l) {
  __builtin_amdgcn_global_load_lds(
      (const __attribute__((address_space(1))) uint32_t*)g,
      (__attribute__((address_space(3))) uint32_t*)l, 16, 0, 0);
}

// ---------------- fp32 -> fp16 convert ----------------
__global__ void cvt_f32_f16(const float* __restrict__ in, u16* __restrict__ out, int n4) {
  int i = blockIdx.x * 256 + threadIdx.x;
  if (i < n4) {
    float4 v = reinterpret_cast<const float4*>(in)[i];
    ushort4 o = make_ushort4(f2h(v.x), f2h(v.y), f2h(v.z), f2h(v.w));
    reinterpret_cast<ushort4*>(out)[i] = o;
  }
}

// ---------------- fp16 GEMM, C[m][n] = sum_k A[m][k]*B[n][k] ----------------
// 128x128 tile, BK=32, 4 waves (2x2), each wave 64x64 via 4x4 16x16x32 MFMAs.
template <int F16OUT>
__global__ __launch_bounds__(256, 2) void gemm_bt(
    const u16* __restrict__ A, const u16* __restrict__ B, void* __restrict__ Cv,
    int M, int N, int K) {
  __shared__ __align__(16) u16 As[128 * 32];
  __shared__ __align__(16) u16 Bs[128 * 32];
  const int t = threadIdx.x;
  const int w = t >> 6, l = t & 63;
  const int bm = blockIdx.y * 128, bn = blockIdx.x * 128;
  const int wr = (w >> 1) * 64, wc = (w & 1) * 64;
  f32x4 acc[4][4] = {};

  const int arow = t >> 2;          // 0..63
  const int acol = (t & 3) * 8;     // ushort offset within 32-elem row
  const u16* Ag0 = A + (size_t)(bm + arow) * K + acol;
  const u16* Ag1 = A + (size_t)(bm + 64 + arow) * K + acol;
  const u16* Bg0 = B + (size_t)(bn + arow) * K + acol;
  const u16* Bg1 = B + (size_t)(bn + 64 + arow) * K + acol;
  u16* Al0 = As + w * 512;
  u16* Al1 = As + 2048 + w * 512;
  u16* Bl0 = Bs + w * 512;
  u16* Bl1 = Bs + 2048 + w * 512;

  const int lr = l & 15;
  const int lko = (l >> 4) * 8;

  for (int k0 = 0; k0 < K; k0 += 32) {
    __syncthreads();
    glds16(Ag0 + k0, Al0);
    glds16(Ag1 + k0, Al1);
    glds16(Bg0 + k0, Bl0);
    glds16(Bg1 + k0, Bl1);
    __syncthreads();
    f16x8 a[4], b[4];
#pragma unroll
    for (int m = 0; m < 4; ++m) a[m] = *(const f16x8*)&As[(wr + m * 16 + lr) * 32 + lko];
#pragma unroll
    for (int n = 0; n < 4; ++n) b[n] = *(const f16x8*)&Bs[(wc + n * 16 + lr) * 32 + lko];
#pragma unroll
    for (int m = 0; m < 4; ++m)
#pragma unroll
      for (int n = 0; n < 4; ++n)
        acc[m][n] = __builtin_amdgcn_mfma_f32_16x16x32_f16(a[m], b[n], acc[m][n], 0, 0, 0);
  }

#pragma unroll
  for (int m = 0; m < 4; ++m) {
#pragma unroll
    for (int n = 0; n < 4; ++n) {
      const int col = bn + wc + n * 16 + lr;
      const int row0 = bm + wr + m * 16 + (l >> 4) * 4;
#pragma unroll
      for (int j = 0; j < 4; ++j) {
        float vv = acc[m][n][j];
        if constexpr (F16OUT)
          ((u16*)Cv)[(size_t)(row0 + j) * N + col] = f2h(vv);
        else
          ((float*)Cv)[(size_t)(row0 + j) * N + col] = vv;
      }
    }
  }
}

// ---------------- RMSNorm + RoPE, qkv(f16) -> q[h][s][d], k[h][s][d], vT[h][d][s] ----------------
__global__ void norm_rope(const u16* __restrict__ qkv, const float* __restrict__ qw,
                          const float* __restrict__ kw, const int* __restrict__ pos,
                          u16* __restrict__ qo, u16* __restrict__ ko, u16* __restrict__ vt) {
  const int b = blockIdx.x;
  const int s = b >> 5;
  const int slot = b & 31;   // 0..15 q heads, 16..23 k heads, 24..31 v heads
  const int l = threadIdx.x; // 64 threads, 4 elems each
  const u16* row = qkv + (size_t)s * QKVN + slot * HD;
  ushort4 rv = *reinterpret_cast<const ushort4*>(row + l * 4);
  float x0 = h2f(rv.x), x1 = h2f(rv.y), x2 = h2f(rv.z), x3 = h2f(rv.w);
  float ss = x0 * x0 + x1 * x1 + x2 * x2 + x3 * x3;
#pragma unroll
  for (int mk = 32; mk; mk >>= 1) ss += __shfl_xor(ss, mk);
  const float rs = rsqrtf(ss * (1.0f / 256.0f) + 1e-6f);
  float n0, n1, n2, n3;
  if (slot < 16) {
    float4 wv = *reinterpret_cast<const float4*>(qw + l * 4);
    n0 = x0 * rs * (1.f + wv.x); n1 = x1 * rs * (1.f + wv.y);
    n2 = x2 * rs * (1.f + wv.z); n3 = x3 * rs * (1.f + wv.w);
  } else if (slot < 24) {
    float4 wv = *reinterpret_cast<const float4*>(kw + l * 4);
    n0 = x0 * rs * (1.f + wv.x); n1 = x1 * rs * (1.f + wv.y);
    n2 = x2 * rs * (1.f + wv.z); n3 = x3 * rs * (1.f + wv.w);
  } else {
    n0 = x0 * rs; n1 = x1 * rs; n2 = x2 * rs; n3 = x3 * rs;
  }
  if (slot < 24) {  // RoPE on first 64 dims (lanes 0..15): pairs (d, d+32)
    float p0 = __shfl_xor(n0, 8), p1 = __shfl_xor(n1, 8);
    float p2 = __shfl_xor(n2, 8), p3 = __shfl_xor(n3, 8);
    if (l < 16) {
      const double posd = (double)pos[s];
      float v[4] = {n0, n1, n2, n3};
      const float par[4] = {p0, p1, p2, p3};
#pragma unroll
      for (int i = 0; i < 4; ++i) {
        const int d = l * 4 + i;
        const int fi = d & 31;
        // inv = 10000^(-fi/32), phase = pos*inv, range-reduced in double so the
        // fp32 sincos sees a small exact-ish argument (matches the fp64 np ref)
        double inv = exp2(-(double)fi * (13.287712379549449 / 32.0));
        double ph = posd * inv;
        double tr = ph * 0.15915494309189535;  // / 2pi
        tr -= floor(tr);
        float ang = (float)(tr * 6.283185307179586);
        float sn, cs;
        sincosf(ang, &sn, &cs);
        v[i] = (d < 32) ? (v[i] * cs - par[i] * sn) : (v[i] * cs + par[i] * sn);
      }
      n0 = v[0]; n1 = v[1]; n2 = v[2]; n3 = v[3];
    }
  }
  if (slot < 16) {
    ushort4 o = make_ushort4(f2h(n0), f2h(n1), f2h(n2), f2h(n3));
    *reinterpret_cast<ushort4*>(qo + ((size_t)slot * SEQ + s) * HD + l * 4) = o;
  } else if (slot < 24) {
    ushort4 o = make_ushort4(f2h(n0), f2h(n1), f2h(n2), f2h(n3));
    *reinterpret_cast<ushort4*>(ko + ((size_t)(slot - 16) * SEQ + s) * HD + l * 4) = o;
  } else {
    u16* base = vt + (size_t)(slot - 24) * HD * SEQ + s;
    base[(size_t)(l * 4 + 0) * SEQ] = f2h(n0);
    base[(size_t)(l * 4 + 1) * SEQ] = f2h(n1);
    base[(size_t)(l * 4 + 2) * SEQ] = f2h(n2);
    base[(size_t)(l * 4 + 3) * SEQ] = f2h(n3);
  }
}

// ---------------- causal flash attention ----------------
// grid (SEQ/64, NH); block 256 (4 waves x 16 q-rows). KV tiles of 64.
// K staged [64][256] f16 with 16B-chunk XOR swizzle (chunk ^ (row&7));
// V staged transposed [256][64] with same swizzle. Swizzle applied on the
// *global source* address (global_load_lds writes LDS linearly).
__global__ __launch_bounds__(256, 2) void attn_fwd(
    const u16* __restrict__ Q, const u16* __restrict__ Kb,
    const u16* __restrict__ Vt, u16* __restrict__ O) {
  __shared__ __align__(16) u16 Ks[64 * 256];
  __shared__ __align__(16) u16 Vs[256 * 64];
  __shared__ __align__(16) u16 Ps[4 * 16 * 72];  // per-wave P scratch, 144B row stride
  const int t = threadIdx.x, w = t >> 6, l = t & 63;
  const int bq = (gridDim.x - 1) - blockIdx.x;  // big blocks first
  const int h = blockIdx.y;
  const int hk = h >> 1;
  const int lr = l & 15, lg = l >> 4;

  // Q fragments for this wave's 16 rows (A-operand: row=l&15, k=(l>>4)*8+i)
  const u16* qrow = Q + ((size_t)h * SEQ + bq * 64 + w * 16 + lr) * HD + lg * 8;
  f16x8 qf[8];
#pragma unroll
  for (int c = 0; c < 8; ++c) qf[c] = *(const f16x8*)(qrow + c * 32);

  float m[4], lsum[4];
#pragma unroll
  for (int j = 0; j < 4; ++j) { m[j] = -1e30f; lsum[j] = 0.f; }
  f32x4 oacc[16] = {};

  const int krow_i = t >> 5;  // K stage: row = i*8 + this
  const int kchunk = t & 31;
  const int vrow_i = t >> 3;  // V stage: d = i*32 + this
  const int vchunk = t & 7;
  const u16* Kg = Kb + (size_t)hk * SEQ * HD;
  const u16* Vg = Vt + (size_t)hk * HD * SEQ;

  const int nt = bq + 1;
  for (int tt = 0; tt < nt; ++tt) {
    const int kv0 = tt * 64;
    __syncthreads();
#pragma unroll
    for (int i = 0; i < 8; ++i) {
      int row = i * 8 + krow_i;
      int sc = kchunk ^ (row & 7);
      glds16(Kg + (size_t)(kv0 + row) * HD + sc * 8, Ks + i * 2048 + w * 512);
    }
#pragma unroll
    for (int i = 0; i < 8; ++i) {
      int d = i * 32 + vrow_i;
      int sc = vchunk ^ (d & 7);
      glds16(Vg + (size_t)d * SEQ + kv0 + sc * 8, Vs + i * 2048 + w * 512);
    }
    __syncthreads();

    // S = Q K^T : 16 q-rows x 64 kv-cols
    f32x4 sv[4];
#pragma unroll
    for (int n = 0; n < 4; ++n) {
      f32x4 s = {};
      const int krow = n * 16 + lr;
      const int rb = krow * 256;
      const int sw = krow & 7;
#pragma unroll
      for (int c = 0; c < 8; ++c) {
        const int chunk = (c * 4 + lg) ^ sw;
        f16x8 kf = *(const f16x8*)&Ks[rb + chunk * 8];
        s = __builtin_amdgcn_mfma_f32_16x16x32_f16(qf[c], kf, s, 0, 0, 0);
      }
      sv[n] = s;
    }
    // causal mask
    const int qrow0 = bq * 64 + w * 16 + lg * 4;
#pragma unroll
    for (int n = 0; n < 4; ++n) {
      const int col = kv0 + n * 16 + lr;
#pragma unroll
      for (int j = 0; j < 4; ++j)
        if (col > qrow0 + j) sv[n][j] = -1e30f;
    }
    // online softmax (row stats across the 16 lanes of each group)
    float pvv[4][4];
#pragma unroll
    for (int j = 0; j < 4; ++j) {
      float mx = fmaxf(fmaxf(sv[0][j], sv[1][j]), fmaxf(sv[2][j], sv[3][j]));
#pragma unroll
      for (int mk = 8; mk; mk >>= 1) mx = fmaxf(mx, __shfl_xor(mx, mk));
      const float mnew = fmaxf(m[j], mx);
      const float scale = __expf(m[j] - mnew);
      float rsum = 0.f;
#pragma unroll
      for (int n = 0; n < 4; ++n) {
        float e = __expf(sv[n][j] - mnew);
        pvv[n][j] = e;
        rsum += e;
      }
#pragma unroll
      for (int mk = 8; mk; mk >>= 1) rsum += __shfl_xor(rsum, mk);
      lsum[j] = lsum[j] * scale + rsum;
      m[j] = mnew;
#pragma unroll
      for (int nc = 0; nc < 16; ++nc) oacc[nc][j] *= scale;
    }
    // P -> LDS (re-layout for PV A-operand)
    u16* pb = Ps + w * 1152;
#pragma unroll
    for (int n = 0; n < 4; ++n)
#pragma unroll
      for (int j = 0; j < 4; ++j)
        pb[(lg * 4 + j) * 72 + n * 16 + lr] = f2h(pvv[n][j]);
    // O += P V
#pragma unroll
    for (int kk = 0; kk < 2; ++kk) {
      f16x8 pa = *(const f16x8*)&pb[lr * 72 + kk * 32 + lg * 8];
#pragma unroll
      for (int nc = 0; nc < 16; ++nc) {
        const int drow = nc * 16 + lr;
        const int chunk = (kk * 4 + lg) ^ (drow & 7);
        f16x8 vf = *(const f16x8*)&Vs[drow * 64 + chunk * 8];
        oacc[nc] = __builtin_amdgcn_mfma_f32_16x16x32_f16(pa, vf, oacc[nc], 0, 0, 0);
      }
    }
  }
  // epilogue: normalize and store f16 [s][h*256+d]
  float rl[4];
#pragma unroll
  for (int j = 0; j < 4; ++j) rl[j] = __fdividef(1.f, lsum[j]);
#pragma unroll
  for (int nc = 0; nc < 16; ++nc) {
#pragma unroll
    for (int j = 0; j < 4; ++j) {
      const int qr = bq * 64 + w * 16 + lg * 4 + j;
      O[(size_t)qr * QSZ + h * HD + nc * 16 + lr] = f2h(oacc[nc][j] * rl[j]);
    }
  }
}

extern "C" void kernel_launch(void* const* d_in, const int* in_sizes, int n_in,
                              void* d_out, int out_size, void* d_ws, size_t ws_size,
                              hipStream_t stream) {
  const int* pos = (const int*)d_in[0];
  const float* hidden = (const float*)d_in[1];
  const float* wqkv = (const float*)d_in[2];
  const float* qw = (const float*)d_in[3];
  const float* kw = (const float*)d_in[4];
  const float* wo_f = (const float*)d_in[5];
  float* out = (float*)d_out;

  // workspace layout (88 MiB total, with region reuse):
  // [0,8M)   hb   (hidden f16)         -> dead after GEMM1
  // [8,40M)  wqb  (w_qkv f16)          -> dead after GEMM1
  // [40,56M) wob  (w_o f16)            -> live until GEMM2
  // [56,88M) qkvb (qkv f16)            -> dead after norm_rope
  // [0,16M)  qb   [16][2048][256]      (overlays hb+wqb)
  // [16,24M) kb   [8][2048][256]
  // [24,32M) vt   [8][256][2048]       (V transposed)
  // [56,72M) ao   attn out f16         (overlays qkvb)
  char* wsp = (char*)d_ws;
  u16* hb = (u16*)(wsp);
  u16* wqb = (u16*)(wsp + (8ll << 20));
  u16* wob = (u16*)(wsp + (40ll << 20));
  u16* qkvb = (u16*)(wsp + (56ll << 20));
  u16* qb = (u16*)(wsp);
  u16* kb = (u16*)(wsp + (16ll << 20));
  u16* vt = (u16*)(wsp + (24ll << 20));
  u16* ao = (u16*)(wsp + (56ll << 20));

  cvt_f32_f16<<<(HID * HID / 4 + 255) / 256, 256, 0, stream>>>(hidden, hb, HID * HID / 4);
  cvt_f32_f16<<<(QKVN * HID / 4 + 255) / 256, 256, 0, stream>>>(wqkv, wqb, QKVN * HID / 4);
  cvt_f32_f16<<<(HID * QSZ / 4 + 255) / 256, 256, 0, stream>>>(wo_f, wob, HID * QSZ / 4);

  gemm_bt<1><<<dim3(QKVN / 128, SEQ / 128), 256, 0, stream>>>(hb, wqb, (void*)qkvb, SEQ, QKVN, HID);
  norm_rope<<<SEQ * 32, 64, 0, stream>>>(qkvb, qw, kw, pos, qb, kb, vt);
  attn_fwd<<<dim3(SEQ / 64, NH), 256, 0, stream>>>(qb, kb, vt, ao);
  gemm_bt<0><<<dim3(HID / 128, SEQ / 128), 256, 0, stream>>>(ao, wob, (void*)out, SEQ, HID, QSZ);
}